// Round 2
// baseline (456.593 us; speedup 1.0000x reference)
//
#include <hip/hip_runtime.h>
#include <hip/hip_bf16.h>

#define BB 32
#define SS 4096
#define HH 512
#define EE 512
#define NCH 64          // 64-row s-chunks per b
#define QSEG 8          // split-K segments for q-projection
#define NEGV -1000000000.0f

using float4v = __attribute__((ext_vector_type(4))) float;
using short8v = __attribute__((ext_vector_type(8))) short;

#if defined(__has_builtin)
#if __has_builtin(__builtin_amdgcn_sched_barrier)
#define SCHED_FENCE() __builtin_amdgcn_sched_barrier(0)
#endif
#if __has_builtin(__builtin_amdgcn_rcpf)
#define FAST_RCP(x) __builtin_amdgcn_rcpf(x)
#endif
#if __has_builtin(__builtin_amdgcn_exp2f)
#define FAST_EXP2(x) __builtin_amdgcn_exp2f(x)
#endif
#if __has_builtin(__builtin_amdgcn_s_setprio)
#define SETPRIO(n) __builtin_amdgcn_s_setprio(n)
#endif
#endif
#ifndef SCHED_FENCE
#define SCHED_FENCE()
#endif
#ifndef FAST_RCP
#define FAST_RCP(x) (1.0f / (x))
#endif
#ifndef FAST_EXP2
#define FAST_EXP2(x) __expf(0.69314718056f * (x))
#endif
#ifndef SETPRIO
#define SETPRIO(n)
#endif

__device__ inline unsigned short f2bf(float x) {
    union { float f; unsigned int u; } c; c.f = x;
    unsigned int r = c.u + 0x7FFFu + ((c.u >> 16) & 1u);  // RNE
    return (unsigned short)(r >> 16);
}
__device__ inline float bf2f(unsigned short s) {
    union { float f; unsigned int u; } c; c.u = ((unsigned int)s) << 16;
    return c.f;
}
__device__ inline unsigned int pk2bf(float a, float b) {  // packed RNE cvt
    union { __hip_bfloat162 h; unsigned int u; } c;
    c.h = __float22bfloat162_rn(float2{a, b});
    return c.u;
}

// Merged prep: blocks [0,256) compute 8-way split-K q-projection partials;
// blocks [256,384) repack Wk (E,H) fp32 -> fragment-linear bf16 via an LDS
// transpose tile so the global reads are fully coalesced (256B bursts).
__global__ void prep_kernel(const float* __restrict__ query, const float* __restrict__ Wq,
                            float* __restrict__ qp8,
                            const float* __restrict__ Wk, unsigned short* __restrict__ WkT) {
    int bx = blockIdx.x, t = threadIdx.x;  // 256 threads
    if (bx < QSEG * BB) {
        __shared__ float qs[64];
        int b = bx >> 3, seg = bx & 7;
        if (t < 64) qs[t] = query[b * HH + seg * 64 + t];
        __syncthreads();
        float a0 = 0.f, a1 = 0.f;
        const float* wq = Wq + (size_t)(seg * 64) * HH;
        #pragma unroll 8
        for (int e = 0; e < 64; ++e) {
            float q = qs[e];
            a0 += q * wq[(size_t)e * HH + t];
            a1 += q * wq[(size_t)e * HH + t + 256];
        }
        qp8[((size_t)seg * BB + b) * HH + t] = a0;
        qp8[((size_t)seg * BB + b) * HH + t + 256] = a1;
    } else {
        // tile: 32 e-rows (one ks slice) x 64 h-cols; 128 blocks total
        int tile = bx - QSEG * BB;      // 0..127
        int ks = tile >> 3;             // 0..15 -> e0 = ks*32
        int h0 = (tile & 7) * 64;       // h tile base
        __shared__ float wt[32][67];    // 67-stride: lq rows land on distinct banks
        #pragma unroll
        for (int p = 0; p < 2; ++p) {
            int idx = t + p * 256;      // 512 float4 groups: 16 per row, 32 rows
            int r = idx >> 4, c4 = idx & 15;
            float4v wv = *(const float4v*)(Wk + (size_t)(ks * 32 + r) * HH + h0 + c4 * 4);
            wt[r][c4 * 4 + 0] = wv.x; wt[r][c4 * 4 + 1] = wv.y;
            wt[r][c4 * 4 + 2] = wv.z; wt[r][c4 * 4 + 3] = wv.w;
        }
        __syncthreads();
        int lane = t & 63, ntl = t >> 6;      // 4 nt per tile, one frag per thread
        int lq = lane >> 4, lr = lane & 15;
        int nt = (h0 >> 4) + ntl;
        short8v o;
        #pragma unroll
        for (int j = 0; j < 8; ++j)
            o[j] = (short)f2bf(wt[lq * 8 + j][ntl * 16 + lr]);
        size_t g = ((size_t)ks * 32 + nt) * 64 + lane;
        *(short8v*)(WkT + g * 8) = o;
    }
}

// Fused scores + online-softmax stats + context partial. grid (NCH, B), 512 thr.
// Keys tile staged in four 128-col segments. Next segment's HBM loads are issued
// before this segment's MFMAs; its cvt+LDS-store is hoisted into k-slice 2
// (disjoint LDS columns, data back from HBM by then) so only the barrier is
// exposed. WkT fragments are register double-buffered one k-slice ahead.
__launch_bounds__(512, 4)
__global__ void fused_kernel(const float* __restrict__ keys, const unsigned short* __restrict__ WkT,
                             const float* __restrict__ qp8, const float* __restrict__ bq,
                             const float* __restrict__ bk, const float* __restrict__ v,
                             const float* __restrict__ bv, const int* __restrict__ mask,
                             float* __restrict__ pe_out, float* __restrict__ part,
                             float* __restrict__ marr, float* __restrict__ larr) {
    constexpr int LDK = EE + 8;                 // 520 shorts, 1040B row stride
    __shared__ unsigned short klds[64 * LDK];   // 66.5 KB
    __shared__ float qp_lds[HH];
    __shared__ float v_lds[HH];
    __shared__ float red[8][64];
    __shared__ float p_lds[64];
    __shared__ float ctxred[2][EE];             // 4 KB (total ~77 KB, 2 blocks/CU)
    int b = blockIdx.y, c = blockIdx.x, s0 = c * 64;
    int tid = threadIdx.x;

    // issue segment-0 keys loads first (earliest HBM), then small L2 reads
    const float4v* ksrc = (const float4v*)(keys + ((size_t)b * SS + s0) * EE);
    float4v kv[4];
    #pragma unroll
    for (int p = 0; p < 4; ++p) {
        int idx = tid + p * 512;
        kv[p] = ksrc[(size_t)(idx >> 5) * 128 + (idx & 31)];
    }
    int mval = 0;
    if (tid < 64) mval = mask[b * SS + s0 + tid];  // prefetch; used at the end

    for (int i = tid; i < HH; i += 512) {
        float qv = 0.f;
        #pragma unroll
        for (int sg = 0; sg < QSEG; ++sg) qv += qp8[((size_t)sg * BB + b) * HH + i];
        qp_lds[i] = qv + bq[i] + bk[i];
        v_lds[i] = v[i];
    }

    #pragma unroll
    for (int p = 0; p < 4; ++p) {
        int idx = tid + p * 512, row = idx >> 5, c4 = idx & 31;
        unsigned int u0 = pk2bf(kv[p].x, kv[p].y), u1 = pk2bf(kv[p].z, kv[p].w);
        *(uint2*)(&klds[row * LDK + c4 * 4]) = make_uint2(u0, u1);
    }

    int w = tid >> 6, lane = tid & 63;
    int lq = lane >> 4, lr = lane & 15;
    int nt0 = w * 4;
    const short8v* Wf = (const short8v*)WkT;

    // preload k-slice 0's B fragments before the barrier (overlaps barrier wait)
    short8v bcur[4];
    #pragma unroll
    for (int j = 0; j < 4; ++j) bcur[j] = Wf[(size_t)(nt0 + j) * 64 + lane];

    float4v acc[4][4];
    #pragma unroll
    for (int m = 0; m < 4; ++m)
        #pragma unroll
        for (int j = 0; j < 4; ++j) acc[m][j] = (float4v){0.f, 0.f, 0.f, 0.f};

    __syncthreads();

    #pragma unroll
    for (int q = 0; q < 4; ++q) {
        if (q < 3) {  // issue next segment's HBM loads; fence pins them above the MFMAs
            #pragma unroll
            for (int p = 0; p < 4; ++p) {
                int idx = tid + p * 512;
                kv[p] = ksrc[(size_t)(idx >> 5) * 128 + (q + 1) * 32 + (idx & 31)];
            }
        }
        SCHED_FENCE();
        #pragma unroll
        for (int ksl = 0; ksl < 4; ++ksl) {
            int kq = q * 4 + ksl;
            short8v bn[4];
            if (kq < 15) {  // prefetch next k-slice's B fragments (compile-time guard)
                #pragma unroll
                for (int j = 0; j < 4; ++j)
                    bn[j] = Wf[((size_t)(kq + 1) * 32 + nt0 + j) * 64 + lane];
            }
            SETPRIO(1);
            #pragma unroll
            for (int m = 0; m < 4; ++m) {
                short8v afrag = *(const short8v*)(&klds[(m * 16 + lr) * LDK + kq * 32 + lq * 8]);
                #pragma unroll
                for (int j = 0; j < 4; ++j)
                    acc[m][j] = __builtin_amdgcn_mfma_f32_16x16x32_bf16(afrag, bcur[j], acc[m][j], 0, 0, 0);
            }
            SETPRIO(0);
            if (kq < 15) {
                #pragma unroll
                for (int j = 0; j < 4; ++j) bcur[j] = bn[j];
            }
            if (ksl == 2 && q < 3) {
                // hoisted cvt+store of seg q+1 (LDS cols disjoint from seg q reads;
                // kv returned from HBM under ~3 k-slices of MFMA). Slice 3's MFMAs
                // then overlap the ds_write drain; only the barrier stays exposed.
                #pragma unroll
                for (int p = 0; p < 4; ++p) {
                    int idx = tid + p * 512, row = idx >> 5, c4 = (q + 1) * 32 + (idx & 31);
                    unsigned int u0 = pk2bf(kv[p].x, kv[p].y), u1 = pk2bf(kv[p].z, kv[p].w);
                    *(uint2*)(&klds[row * LDK + c4 * 4]) = make_uint2(u0, u1);
                }
            }
        }
        if (q < 3) __syncthreads();
    }

    // tanh epilogue: part += v[h] - 2 v[h] / (2^(2/ln2 * x)+1)   (== v[h]*tanh(x))
    float part_r[4][4];
    #pragma unroll
    for (int m = 0; m < 4; ++m)
        #pragma unroll
        for (int r = 0; r < 4; ++r) part_r[m][r] = 0.f;
    #pragma unroll
    for (int j = 0; j < 4; ++j) {
        int h = (nt0 + j) * 16 + lr;
        float vj = v_lds[h], qj = qp_lds[h], vj2 = -2.f * vj;
        #pragma unroll
        for (int m = 0; m < 4; ++m) {
            #pragma unroll
            for (int r = 0; r < 4; ++r) {
                float x = qj + acc[m][j][r];
                float rr = FAST_RCP(FAST_EXP2(2.885390082f * x) + 1.f);
                part_r[m][r] += __builtin_fmaf(vj2, rr, vj);
            }
        }
    }
    #pragma unroll
    for (int m = 0; m < 4; ++m)
        #pragma unroll
        for (int r = 0; r < 4; ++r) {
            float p = part_r[m][r];
            p += __shfl_xor(p, 1, 16);
            p += __shfl_xor(p, 2, 16);
            p += __shfl_xor(p, 4, 16);
            p += __shfl_xor(p, 8, 16);
            part_r[m][r] = p;
        }
    if (lr == 0) {
        #pragma unroll
        for (int m = 0; m < 4; ++m)
            #pragma unroll
            for (int r = 0; r < 4; ++r)
                red[w][m * 16 + lq * 4 + r] = part_r[m][r];
    }
    __syncthreads();

    // wave 0: final score, mask, chunk-local softmax stats; store pe (not raw score)
    if (tid < 64) {
        float sc = red[0][tid] + red[1][tid] + red[2][tid] + red[3][tid]
                 + red[4][tid] + red[5][tid] + red[6][tid] + red[7][tid] + bv[0];
        if (mval == 0) sc = NEGV;
        float mv = sc;
        #pragma unroll
        for (int off = 1; off < 64; off <<= 1) mv = fmaxf(mv, __shfl_xor(mv, off));
        float pe = __expf(sc - mv);
        float ls = pe;
        #pragma unroll
        for (int off = 1; off < 64; off <<= 1) ls += __shfl_xor(ls, off);
        p_lds[tid] = pe;
        pe_out[b * SS + s0 + tid] = pe;
        if (tid == 0) { marr[b * NCH + c] = mv; larr[b * NCH + c] = ls; }
    }
    __syncthreads();

    // context partial from the retained LDS tile: o[e] = sum_s p[s]*keys[s][e]
    // paired-b32 reads (2 cols/load) + row-split across thread halves: 32 LDS
    // ops/thread instead of 64 scalar u16 reads.
    {
        int c2 = (tid & 255) * 2;
        int sb = (tid >> 8) * 32;
        float e0 = 0.f, e1 = 0.f;
        #pragma unroll 8
        for (int s = 0; s < 32; ++s) {
            unsigned int u = *(const unsigned int*)(&klds[(sb + s) * LDK + c2]);
            float ps = p_lds[sb + s];
            e0 = __builtin_fmaf(ps, bf2f((unsigned short)(u & 0xffffu)), e0);
            e1 = __builtin_fmaf(ps, bf2f((unsigned short)(u >> 16)), e1);
        }
        *(float2*)(&ctxred[tid >> 8][c2]) = make_float2(e0, e1);
    }
    __syncthreads();
    part[((size_t)b * NCH + c) * EE + tid] = ctxred[0][tid] + ctxred[1][tid];
}

// Merge chunk partials; grid (4, B): x==0 writes ctx, all x write attn slices.
// attn[s] = pe[s] * exp(m_chunk - M) / L  (identical math, no re-exp of scores)
__global__ void finalize_kernel(const float* __restrict__ pe_arr, const float* __restrict__ part,
                                const float* __restrict__ marr, const float* __restrict__ larr,
                                float* __restrict__ ctx, float* __restrict__ attn) {
    __shared__ float wgt[NCH];
    __shared__ float Ls;
    int b = blockIdx.y, px = blockIdx.x, t = threadIdx.x;  // 512 threads
    if (t < NCH) {
        float m = marr[b * NCH + t], l = larr[b * NCH + t];
        float M = m;
        #pragma unroll
        for (int off = 1; off < 64; off <<= 1) M = fmaxf(M, __shfl_xor(M, off));
        float wq = __expf(m - M);
        float L = wq * l;
        #pragma unroll
        for (int off = 1; off < 64; off <<= 1) L += __shfl_xor(L, off);
        wgt[t] = wq;
        if (t == 0) Ls = L;
    }
    __syncthreads();
    float invL = 1.f / Ls;
    if (px == 0) {
        float o = 0.f;
        #pragma unroll 8
        for (int cc = 0; cc < NCH; ++cc)
            o += wgt[cc] * part[((size_t)b * NCH + cc) * EE + t];
        ctx[b * EE + t] = o * invL;
    }
    int s0 = px * 1024;
    attn[b * SS + s0 + t]       = pe_arr[b * SS + s0 + t]       * wgt[(s0 + t) >> 6]       * invL;
    attn[b * SS + s0 + t + 512] = pe_arr[b * SS + s0 + t + 512] * wgt[(s0 + t + 512) >> 6] * invL;
}

extern "C" void kernel_launch(void* const* d_in, const int* in_sizes, int n_in,
                              void* d_out, int out_size, void* d_ws, size_t ws_size,
                              hipStream_t stream) {
    const float* query = (const float*)d_in[0];
    const float* keys  = (const float*)d_in[1];
    const int*   mask  = (const int*)d_in[2];
    const float* Wq    = (const float*)d_in[3];
    const float* bq    = (const float*)d_in[4];
    const float* Wk    = (const float*)d_in[5];
    const float* bk    = (const float*)d_in[6];
    const float* v     = (const float*)d_in[7];
    const float* bv    = (const float*)d_in[8];

    float* out  = (float*)d_out;
    float* ctx  = out;            // (B, E)
    float* attn = out + BB * EE;  // (B, S)

    char* ws = (char*)d_ws;
    float* qp8          = (float*)ws;                         // 8*32*512*4 = 524288 B
    unsigned short* WkT = (unsigned short*)(ws + 524288);     // 524288 B
    float* pe           = (float*)(ws + 1048576);             // 524288 B
    float* part         = (float*)(ws + 1572864);             // 4194304 B
    float* marr         = (float*)(ws + 5767168);             // 8192 B
    float* larr         = (float*)(ws + 5775360);             // 8192 B

    prep_kernel<<<QSEG * BB + 128, 256, 0, stream>>>(query, Wq, qp8, Wk, WkT);
    fused_kernel<<<dim3(NCH, BB), 512, 0, stream>>>(keys, WkT, qp8, bq, bk, v, bv, mask,
                                                    pe, part, marr, larr);
    finalize_kernel<<<dim3(4, BB), 512, 0, stream>>>(pe, part, marr, larr, ctx, attn);
}

// Round 3
// 436.617 us; speedup vs baseline: 1.0458x; 1.0458x over previous
//
#include <hip/hip_runtime.h>
#include <hip/hip_bf16.h>

#define BB 32
#define SS 4096
#define HH 512
#define EE 512
#define NCH 64          // 64-row s-chunks per b
#define QSEG 8          // split-K segments for q-projection
#define NEGV -1000000000.0f

using float4v = __attribute__((ext_vector_type(4))) float;
using short8v = __attribute__((ext_vector_type(8))) short;

#if defined(__has_builtin)
#if __has_builtin(__builtin_amdgcn_sched_barrier)
#define SCHED_FENCE() __builtin_amdgcn_sched_barrier(0)
#endif
#if __has_builtin(__builtin_amdgcn_rcpf)
#define FAST_RCP(x) __builtin_amdgcn_rcpf(x)
#endif
#if __has_builtin(__builtin_amdgcn_exp2f)
#define FAST_EXP2(x) __builtin_amdgcn_exp2f(x)
#endif
#if __has_builtin(__builtin_amdgcn_s_setprio)
#define SETPRIO(n) __builtin_amdgcn_s_setprio(n)
#endif
#endif
#ifndef SCHED_FENCE
#define SCHED_FENCE()
#endif
#ifndef FAST_RCP
#define FAST_RCP(x) (1.0f / (x))
#endif
#ifndef FAST_EXP2
#define FAST_EXP2(x) __expf(0.69314718056f * (x))
#endif
#ifndef SETPRIO
#define SETPRIO(n)
#endif

__device__ inline unsigned short f2bf(float x) {
    union { float f; unsigned int u; } c; c.f = x;
    unsigned int r = c.u + 0x7FFFu + ((c.u >> 16) & 1u);  // RNE
    return (unsigned short)(r >> 16);
}
__device__ inline float bf2f(unsigned short s) {
    union { float f; unsigned int u; } c; c.u = ((unsigned int)s) << 16;
    return c.f;
}
__device__ inline unsigned int pk2bf(float a, float b) {  // packed RNE cvt
    union { __hip_bfloat162 h; unsigned int u; } c;
    c.h = __float22bfloat162_rn(float2{a, b});
    return c.u;
}

// Merged prep: blocks [0,256) compute 8-way split-K q-projection partials;
// blocks [256,384) repack Wk (E,H) fp32 -> fragment-linear bf16 via an LDS
// transpose tile so the global reads are fully coalesced (256B bursts).
__global__ void prep_kernel(const float* __restrict__ query, const float* __restrict__ Wq,
                            float* __restrict__ qp8,
                            const float* __restrict__ Wk, unsigned short* __restrict__ WkT) {
    int bx = blockIdx.x, t = threadIdx.x;  // 256 threads
    if (bx < QSEG * BB) {
        __shared__ float qs[64];
        int b = bx >> 3, seg = bx & 7;
        if (t < 64) qs[t] = query[b * HH + seg * 64 + t];
        __syncthreads();
        float a0 = 0.f, a1 = 0.f;
        const float* wq = Wq + (size_t)(seg * 64) * HH;
        #pragma unroll 8
        for (int e = 0; e < 64; ++e) {
            float q = qs[e];
            a0 += q * wq[(size_t)e * HH + t];
            a1 += q * wq[(size_t)e * HH + t + 256];
        }
        qp8[((size_t)seg * BB + b) * HH + t] = a0;
        qp8[((size_t)seg * BB + b) * HH + t + 256] = a1;
    } else {
        // tile: 32 e-rows (one ks slice) x 64 h-cols; 128 blocks total
        int tile = bx - QSEG * BB;      // 0..127
        int ks = tile >> 3;             // 0..15 -> e0 = ks*32
        int h0 = (tile & 7) * 64;       // h tile base
        __shared__ float wt[32][67];    // 67-stride: lq rows land on distinct banks
        #pragma unroll
        for (int p = 0; p < 2; ++p) {
            int idx = t + p * 256;      // 512 float4 groups: 16 per row, 32 rows
            int r = idx >> 4, c4 = idx & 15;
            float4v wv = *(const float4v*)(Wk + (size_t)(ks * 32 + r) * HH + h0 + c4 * 4);
            wt[r][c4 * 4 + 0] = wv.x; wt[r][c4 * 4 + 1] = wv.y;
            wt[r][c4 * 4 + 2] = wv.z; wt[r][c4 * 4 + 3] = wv.w;
        }
        __syncthreads();
        int lane = t & 63, ntl = t >> 6;      // 4 nt per tile, one frag per thread
        int lq = lane >> 4, lr = lane & 15;
        int nt = (h0 >> 4) + ntl;
        short8v o;
        #pragma unroll
        for (int j = 0; j < 8; ++j)
            o[j] = (short)f2bf(wt[lq * 8 + j][ntl * 16 + lr]);
        size_t g = ((size_t)ks * 32 + nt) * 64 + lane;
        *(short8v*)(WkT + g * 8) = o;
    }
}

// Fused scores + online-softmax stats + context partial. grid (NCH, B), 512 thr.
// Keys tile staged in four 128-col segments. Next segment's HBM loads are issued
// before this segment's MFMAs; its cvt+LDS-store is hoisted into k-slice 2.
// WkT fragments are register double-buffered one k-slice ahead.
// launch_bounds(512, 2): 256 VGPR/wave budget so the pipeline buffers
// (acc 64 AGPR + bcur/bn/kv 48 VGPR) stay in registers — at (512,4) the
// 128-reg cap spilled them to scratch (182 MB of HBM write traffic, r2).
__launch_bounds__(512, 2)
__global__ void fused_kernel(const float* __restrict__ keys, const unsigned short* __restrict__ WkT,
                             const float* __restrict__ qp8, const float* __restrict__ bq,
                             const float* __restrict__ bk, const float* __restrict__ v,
                             const float* __restrict__ bv, const int* __restrict__ mask,
                             float* __restrict__ pe_out, float* __restrict__ part,
                             float* __restrict__ marr, float* __restrict__ larr) {
    constexpr int LDK = EE + 8;                 // 520 shorts, 1040B row stride
    __shared__ unsigned short klds[64 * LDK];   // 66.5 KB
    __shared__ float qp_lds[HH];
    __shared__ float v_lds[HH];
    __shared__ float red[8][64];
    __shared__ float p_lds[64];
    __shared__ float ctxred[2][EE];             // 4 KB
    int b = blockIdx.y, c = blockIdx.x, s0 = c * 64;
    int tid = threadIdx.x;

    // issue segment-0 keys loads first (earliest HBM), then small L2 reads
    const float4v* ksrc = (const float4v*)(keys + ((size_t)b * SS + s0) * EE);
    float4v kv[4];
    #pragma unroll
    for (int p = 0; p < 4; ++p) {
        int idx = tid + p * 512;
        kv[p] = ksrc[(size_t)(idx >> 5) * 128 + (idx & 31)];
    }
    int mval = 0;
    if (tid < 64) mval = mask[b * SS + s0 + tid];  // prefetch; used at the end

    for (int i = tid; i < HH; i += 512) {
        float qv = 0.f;
        #pragma unroll
        for (int sg = 0; sg < QSEG; ++sg) qv += qp8[((size_t)sg * BB + b) * HH + i];
        qp_lds[i] = qv + bq[i] + bk[i];
        v_lds[i] = v[i];
    }

    #pragma unroll
    for (int p = 0; p < 4; ++p) {
        int idx = tid + p * 512, row = idx >> 5, c4 = idx & 31;
        unsigned int u0 = pk2bf(kv[p].x, kv[p].y), u1 = pk2bf(kv[p].z, kv[p].w);
        *(uint2*)(&klds[row * LDK + c4 * 4]) = make_uint2(u0, u1);
    }

    int w = tid >> 6, lane = tid & 63;
    int lq = lane >> 4, lr = lane & 15;
    int nt0 = w * 4;
    const short8v* Wf = (const short8v*)WkT;

    // preload k-slice 0's B fragments before the barrier (overlaps barrier wait)
    short8v bcur[4];
    #pragma unroll
    for (int j = 0; j < 4; ++j) bcur[j] = Wf[(size_t)(nt0 + j) * 64 + lane];

    float4v acc[4][4];
    #pragma unroll
    for (int m = 0; m < 4; ++m)
        #pragma unroll
        for (int j = 0; j < 4; ++j) acc[m][j] = (float4v){0.f, 0.f, 0.f, 0.f};

    __syncthreads();

    #pragma unroll
    for (int q = 0; q < 4; ++q) {
        if (q < 3) {  // issue next segment's HBM loads; fence pins them above the MFMAs
            #pragma unroll
            for (int p = 0; p < 4; ++p) {
                int idx = tid + p * 512;
                kv[p] = ksrc[(size_t)(idx >> 5) * 128 + (q + 1) * 32 + (idx & 31)];
            }
        }
        SCHED_FENCE();
        #pragma unroll
        for (int ksl = 0; ksl < 4; ++ksl) {
            int kq = q * 4 + ksl;
            short8v bn[4];
            if (kq < 15) {  // prefetch next k-slice's B fragments (compile-time guard)
                #pragma unroll
                for (int j = 0; j < 4; ++j)
                    bn[j] = Wf[((size_t)(kq + 1) * 32 + nt0 + j) * 64 + lane];
            }
            SETPRIO(1);
            #pragma unroll
            for (int m = 0; m < 4; ++m) {
                short8v afrag = *(const short8v*)(&klds[(m * 16 + lr) * LDK + kq * 32 + lq * 8]);
                #pragma unroll
                for (int j = 0; j < 4; ++j)
                    acc[m][j] = __builtin_amdgcn_mfma_f32_16x16x32_bf16(afrag, bcur[j], acc[m][j], 0, 0, 0);
            }
            SETPRIO(0);
            if (kq < 15) {
                #pragma unroll
                for (int j = 0; j < 4; ++j) bcur[j] = bn[j];
            }
            if (ksl == 2 && q < 3) {
                // hoisted cvt+store of seg q+1 (LDS cols disjoint from seg q reads;
                // kv returned from HBM under ~3 k-slices of MFMA). Slice 3's MFMAs
                // then overlap the ds_write drain; only the barrier stays exposed.
                #pragma unroll
                for (int p = 0; p < 4; ++p) {
                    int idx = tid + p * 512, row = idx >> 5, c4 = (q + 1) * 32 + (idx & 31);
                    unsigned int u0 = pk2bf(kv[p].x, kv[p].y), u1 = pk2bf(kv[p].z, kv[p].w);
                    *(uint2*)(&klds[row * LDK + c4 * 4]) = make_uint2(u0, u1);
                }
            }
        }
        if (q < 3) __syncthreads();
    }

    // tanh epilogue: part += v[h] - 2 v[h] / (2^(2/ln2 * x)+1)   (== v[h]*tanh(x))
    float part_r[4][4];
    #pragma unroll
    for (int m = 0; m < 4; ++m)
        #pragma unroll
        for (int r = 0; r < 4; ++r) part_r[m][r] = 0.f;
    #pragma unroll
    for (int j = 0; j < 4; ++j) {
        int h = (nt0 + j) * 16 + lr;
        float vj = v_lds[h], qj = qp_lds[h], vj2 = -2.f * vj;
        #pragma unroll
        for (int m = 0; m < 4; ++m) {
            #pragma unroll
            for (int r = 0; r < 4; ++r) {
                float x = qj + acc[m][j][r];
                float rr = FAST_RCP(FAST_EXP2(2.885390082f * x) + 1.f);
                part_r[m][r] += __builtin_fmaf(vj2, rr, vj);
            }
        }
    }
    #pragma unroll
    for (int m = 0; m < 4; ++m)
        #pragma unroll
        for (int r = 0; r < 4; ++r) {
            float p = part_r[m][r];
            p += __shfl_xor(p, 1, 16);
            p += __shfl_xor(p, 2, 16);
            p += __shfl_xor(p, 4, 16);
            p += __shfl_xor(p, 8, 16);
            part_r[m][r] = p;
        }
    if (lr == 0) {
        #pragma unroll
        for (int m = 0; m < 4; ++m)
            #pragma unroll
            for (int r = 0; r < 4; ++r)
                red[w][m * 16 + lq * 4 + r] = part_r[m][r];
    }
    __syncthreads();

    // wave 0: final score, mask, chunk-local softmax stats; store pe (not raw score)
    if (tid < 64) {
        float sc = red[0][tid] + red[1][tid] + red[2][tid] + red[3][tid]
                 + red[4][tid] + red[5][tid] + red[6][tid] + red[7][tid] + bv[0];
        if (mval == 0) sc = NEGV;
        float mv = sc;
        #pragma unroll
        for (int off = 1; off < 64; off <<= 1) mv = fmaxf(mv, __shfl_xor(mv, off));
        float pe = __expf(sc - mv);
        float ls = pe;
        #pragma unroll
        for (int off = 1; off < 64; off <<= 1) ls += __shfl_xor(ls, off);
        p_lds[tid] = pe;
        pe_out[b * SS + s0 + tid] = pe;
        if (tid == 0) { marr[b * NCH + c] = mv; larr[b * NCH + c] = ls; }
    }
    __syncthreads();

    // context partial from the retained LDS tile: o[e] = sum_s p[s]*keys[s][e]
    // paired-b32 reads (2 cols/load) + row-split across thread halves.
    {
        int c2 = (tid & 255) * 2;
        int sb = (tid >> 8) * 32;
        float e0 = 0.f, e1 = 0.f;
        #pragma unroll 8
        for (int s = 0; s < 32; ++s) {
            unsigned int u = *(const unsigned int*)(&klds[(sb + s) * LDK + c2]);
            float ps = p_lds[sb + s];
            e0 = __builtin_fmaf(ps, bf2f((unsigned short)(u & 0xffffu)), e0);
            e1 = __builtin_fmaf(ps, bf2f((unsigned short)(u >> 16)), e1);
        }
        *(float2*)(&ctxred[tid >> 8][c2]) = make_float2(e0, e1);
    }
    __syncthreads();
    part[((size_t)b * NCH + c) * EE + tid] = ctxred[0][tid] + ctxred[1][tid];
}

// Merge chunk partials; grid (4, B): x==0 writes ctx, all x write attn slices.
// attn[s] = pe[s] * exp(m_chunk - M) / L  (identical math, no re-exp of scores)
__global__ void finalize_kernel(const float* __restrict__ pe_arr, const float* __restrict__ part,
                                const float* __restrict__ marr, const float* __restrict__ larr,
                                float* __restrict__ ctx, float* __restrict__ attn) {
    __shared__ float wgt[NCH];
    __shared__ float Ls;
    int b = blockIdx.y, px = blockIdx.x, t = threadIdx.x;  // 512 threads
    if (t < NCH) {
        float m = marr[b * NCH + t], l = larr[b * NCH + t];
        float M = m;
        #pragma unroll
        for (int off = 1; off < 64; off <<= 1) M = fmaxf(M, __shfl_xor(M, off));
        float wq = __expf(m - M);
        float L = wq * l;
        #pragma unroll
        for (int off = 1; off < 64; off <<= 1) L += __shfl_xor(L, off);
        wgt[t] = wq;
        if (t == 0) Ls = L;
    }
    __syncthreads();
    float invL = 1.f / Ls;
    if (px == 0) {
        float o = 0.f;
        #pragma unroll 8
        for (int cc = 0; cc < NCH; ++cc)
            o += wgt[cc] * part[((size_t)b * NCH + cc) * EE + t];
        ctx[b * EE + t] = o * invL;
    }
    int s0 = px * 1024;
    attn[b * SS + s0 + t]       = pe_arr[b * SS + s0 + t]       * wgt[(s0 + t) >> 6]       * invL;
    attn[b * SS + s0 + t + 512] = pe_arr[b * SS + s0 + t + 512] * wgt[(s0 + t + 512) >> 6] * invL;
}

extern "C" void kernel_launch(void* const* d_in, const int* in_sizes, int n_in,
                              void* d_out, int out_size, void* d_ws, size_t ws_size,
                              hipStream_t stream) {
    const float* query = (const float*)d_in[0];
    const float* keys  = (const float*)d_in[1];
    const int*   mask  = (const int*)d_in[2];
    const float* Wq    = (const float*)d_in[3];
    const float* bq    = (const float*)d_in[4];
    const float* Wk    = (const float*)d_in[5];
    const float* bk    = (const float*)d_in[6];
    const float* v     = (const float*)d_in[7];
    const float* bv    = (const float*)d_in[8];

    float* out  = (float*)d_out;
    float* ctx  = out;            // (B, E)
    float* attn = out + BB * EE;  // (B, S)

    char* ws = (char*)d_ws;
    float* qp8          = (float*)ws;                         // 8*32*512*4 = 524288 B
    unsigned short* WkT = (unsigned short*)(ws + 524288);     // 524288 B
    float* pe           = (float*)(ws + 1048576);             // 524288 B
    float* part         = (float*)(ws + 1572864);             // 4194304 B
    float* marr         = (float*)(ws + 5767168);             // 8192 B
    float* larr         = (float*)(ws + 5775360);             // 8192 B

    prep_kernel<<<QSEG * BB + 128, 256, 0, stream>>>(query, Wq, qp8, Wk, WkT);
    fused_kernel<<<dim3(NCH, BB), 512, 0, stream>>>(keys, WkT, qp8, bq, bk, v, bv, mask,
                                                    pe, part, marr, larr);
    finalize_kernel<<<dim3(4, BB), 512, 0, stream>>>(pe, part, marr, larr, ctx, attn);
}